// Round 4
// baseline (224.957 us; speedup 1.0000x reference)
//
#include <hip/hip_runtime.h>
#include <math.h>

// Problem constants
#define L_SEQ   32768
#define H_DIM   256
#define P_DIM   128
#define P2      256      // 2*P interleaved (re,im)
#define T_CHUNK 32
#define G_CHUNKS 1024    // L_SEQ / T_CHUNK
#define NBLK    256      // GEMM blocks = segments (4 chunks each)

// workspace layout (float offsets)
#define WS_LB    0                      // Lambda_bar            256
#define WS_A32   256                    // Lambda_bar^32         256
#define WS_A128  512                    // Lambda_bar^128        256
#define WS_COEF  768                    // (Lb-1)/Lambda         256
#define WS_APOW  1024                   // [32][P2] Lb^{i+1}     8192
#define WS_E     9216                   // [256][P2] seg summary 65536
#define WS_CB    74752                  // [256][P2] block carry 65536
#define WS_PACKS 140288                 // ushort packs (float offset)
// packs: W1h, W1l, W2h, W2l each 65536 ushorts = 131072 floats total
// grand total = 271360 floats (~1.06 MB)

typedef __attribute__((ext_vector_type(8))) short short8;
typedef __attribute__((ext_vector_type(4))) float f32x4;

// ---------------------------------------------------------------------------
__device__ __forceinline__ void split_bf16(float v, ushort& hi, ushort& lo) {
    union { float f; unsigned u; } a; a.f = v;
    unsigned r = a.u + 0x7FFFu + ((a.u >> 16) & 1u);   // RNE to bf16
    hi = (ushort)(r >> 16);
    union { unsigned u; float f; } hf; hf.u = ((unsigned)hi) << 16;
    float rem = v - hf.f;
    union { float f; unsigned u; } b; b.f = rem;
    unsigned r2 = b.u + 0x7FFFu + ((b.u >> 16) & 1u);
    lo = (ushort)(r2 >> 16);
}

// two packed complex: returns A*x + f  (layout r0,i0,r1,i1)
__device__ __forceinline__ float4 cfma2(const float4 A, const float4 x, const float4 f) {
    float4 o;
    o.x = A.x * x.x - A.y * x.y + f.x;
    o.y = A.x * x.y + A.y * x.x + f.y;
    o.z = A.z * x.z - A.w * x.w + f.z;
    o.w = A.z * x.w + A.w * x.z + f.w;
    return o;
}

// ---------------------------------------------------------------------------
// Setup 1: per-p quantities. 1 block, 128 threads.
__global__ void k_setup_p(const float* __restrict__ lre, const float* __restrict__ lim,
                          const float* __restrict__ lstep, float* __restrict__ ws) {
    int p = threadIdx.x;
    if (p >= P_DIM) return;
    float step = expf(lstep[p]);
    float lr = lre[p], li = lim[p];
    float z = lr * step, y = li * step;
    float er = expf(z);
    ws[WS_LB + 2*p]     = er * cosf(y);
    ws[WS_LB + 2*p + 1] = er * sinf(y);
    // powers in double (large angle => fp32 arg reduction bad)
    double zd = (double)z, yd = (double)y;
    {   // Lb^32 (chunk advance)
        double ed = exp(zd * 32.0);
        ws[WS_A32 + 2*p]     = (float)(ed * cos(yd * 32.0));
        ws[WS_A32 + 2*p + 1] = (float)(ed * sin(yd * 32.0));
    }
    {   // Lb^128 (block/segment advance, 4 chunks)
        double ed = exp(zd * 128.0);
        ws[WS_A128 + 2*p]     = (float)(ed * cos(yd * 128.0));
        ws[WS_A128 + 2*p + 1] = (float)(ed * sin(yd * 128.0));
    }
    // Apow[i] = Lb^{i+1}, i = 0..31
    for (int i = 0; i < 32; i++) {
        double m = (double)(i + 1);
        double ed = exp(zd * m);
        ws[WS_APOW + i*P2 + 2*p]     = (float)(ed * cos(yd * m));
        ws[WS_APOW + i*P2 + 2*p + 1] = (float)(ed * sin(yd * m));
    }
    // coef = (Lambda_bar - 1) / Lambda
    float lbr = ws[WS_LB + 2*p], lbi = ws[WS_LB + 2*p + 1];
    float a = lbr - 1.0f, b = lbi;
    float den = lr*lr + li*li;
    ws[WS_COEF + 2*p]     = (a*lr + b*li) / den;
    ws[WS_COEF + 2*p + 1] = (b*lr - a*li) / den;
}

// ---------------------------------------------------------------------------
// Setup 2: build split-bf16 packed weights, layout [n][k] (k contiguous).
__global__ void k_setup_mats(const float* __restrict__ B, const float* __restrict__ C,
                             const float* __restrict__ coef,
                             ushort* __restrict__ w1h, ushort* __restrict__ w1l,
                             ushort* __restrict__ w2h, ushort* __restrict__ w2l) {
    int t = blockIdx.x * blockDim.x + threadIdx.x;   // 0..16383
    for (int e = t; e < P_DIM * H_DIM; e += 64 * 256) {
        int p = e >> 8;          // 0..127
        int h = e & 255;         // 0..255
        float br = B[(size_t)(p*H_DIM + h)*2 + 0];
        float bi = B[(size_t)(p*H_DIM + h)*2 + 1];
        float cr = coef[2*p], ci = coef[2*p + 1];
        float v1r = cr*br - ci*bi;
        float v1i = cr*bi + ci*br;
        ushort hi, lo;
        split_bf16(v1r, hi, lo);
        w1h[(size_t)(2*p)*256 + h] = hi;  w1l[(size_t)(2*p)*256 + h] = lo;
        split_bf16(v1i, hi, lo);
        w1h[(size_t)(2*p+1)*256 + h] = hi; w1l[(size_t)(2*p+1)*256 + h] = lo;
        float Cr = C[(size_t)(h*P_DIM + p)*2 + 0];
        float Ci = C[(size_t)(h*P_DIM + p)*2 + 1];
        split_bf16(2.0f*Cr, hi, lo);
        w2h[(size_t)h*256 + 2*p] = hi;    w2l[(size_t)h*256 + 2*p] = lo;
        split_bf16(-2.0f*Ci, hi, lo);
        w2h[(size_t)h*256 + 2*p+1] = hi;  w2l[(size_t)h*256 + 2*p+1] = lo;
    }
}

// ---------------------------------------------------------------------------
// Carry: serial scan over 256 block summaries. 1 block, 64 threads.
// cb[s] = carry at start of block s;  cb[s+1] = A128*cb[s] + E[s]
__global__ void k_carry(const float* __restrict__ E, float* __restrict__ cb,
                        const float* __restrict__ a128) {
    const int q = threadIdx.x;   // 0..63
    const float4 A = *(const float4*)(a128 + 4 * q);
    float4 c = make_float4(0.f, 0.f, 0.f, 0.f);
    #pragma unroll 8
    for (int s = 0; s < NBLK; s++) {
        *(float4*)(cb + (size_t)s * P2 + 4 * q) = c;
        const float4 e = *(const float4*)(E + (size_t)s * P2 + 4 * q);
        c = cfma2(A, c, e);
    }
}

// ---------------------------------------------------------------------------
// MFMA split-bf16 GEMM: C[l][n] = sum_k A[l][k] * W[k][n]
// M=32768, N=256 (full N per block -> in-place safe), K=256.
// A: double-buffered LDS (split bf16 on the fly). B: global->register frags.
// APPLY: staging adds Lb^{i+1} * carry (carry rebuilt in LDS from cb + xend rows)
// SCAN : post-epilogue in-place local scan of the block's 4 chunks + E_b out.
#define SAK 40   // LDS k-stride (ushorts): 32 + 8 pad

template<bool EPI, bool APPLY, bool SCAN>
__global__ __launch_bounds__(512, 2) void k_gemm_mfma(
        const float* A, const ushort* __restrict__ Wh, const ushort* __restrict__ Wl,
        float* Cmat, const float* __restrict__ Dv, const float* __restrict__ U,
        const float* __restrict__ ws, float* __restrict__ Eout,
        const float* __restrict__ cbin) {
    __shared__ ushort Ah[2][128 * SAK];
    __shared__ ushort Al[2][128 * SAK];
    __shared__ float  XC[4 * P2];       // Xe (SCAN) or Car (APPLY)
    const int t      = threadIdx.x;
    const int lane   = t & 63;
    const int wave   = t >> 6;        // 0..7
    const int wm     = wave & 3;      // M quarter (32 rows each)
    const int wn     = wave >> 2;     // N half (128 cols each)
    const int lane16 = lane & 15;
    const int quad   = lane >> 4;
    const int blk    = blockIdx.x;
    const int l0     = blk * 128;

    // --- APPLY prologue: rebuild per-chunk carries into LDS ---------------
    if (APPLY) {
        if (t < 64) {
            const float4 A32 = *(const float4*)(ws + WS_A32 + 4 * t);
            float4 c = *(const float4*)(cbin + (size_t)blk * P2 + 4 * t);
            *(float4*)(XC + 4 * t) = c;
            #pragma unroll
            for (int j = 0; j < 3; j++) {
                const float4 xe = *(const float4*)(A + (size_t)(l0 + 32*j + 31) * 256 + 4 * t);
                c = cfma2(A32, c, xe);
                *(float4*)(XC + (j + 1) * P2 + 4 * t) = c;
            }
        }
        __syncthreads();
    }

    f32x4 acc[2][8];
    #pragma unroll
    for (int i = 0; i < 2; i++)
        #pragma unroll
        for (int j = 0; j < 8; j++) acc[i][j] = (f32x4){0.f, 0.f, 0.f, 0.f};

    // staging indices (2 float4 per thread per k-slice)
    const int sm0 = t >> 3;           // row for j=0  (0..63)
    const int sm1 = (512 + t) >> 3;   // row for j=1  (64..127)
    const int sc4 = t & 7;            // float4 col within 32-k slice

    // preload k0 = 0
    float4 f0 = *(const float4*)(A + (size_t)(l0 + sm0) * 256 + sc4 * 4);
    float4 f1 = *(const float4*)(A + (size_t)(l0 + sm1) * 256 + sc4 * 4);

    // b-frag base pointers
    const ushort* WhB = Wh + (size_t)(wn * 128 + lane16) * 256 + quad * 8;
    const ushort* WlB = Wl + (size_t)(wn * 128 + lane16) * 256 + quad * 8;

    #pragma unroll 2
    for (int kt = 0; kt < 8; kt++) {
        const int k0 = kt * 32;
        const int p  = kt & 1;
        // split+store staged A regs into LDS buf p
        {
            float4 ff[2] = {f0, f1};
            int    mm[2] = {sm0, sm1};
            #pragma unroll
            for (int j = 0; j < 2; j++) {
                float4 f = ff[j];
                int m = mm[j];
                if (APPLY) {
                    int g = m >> 5, i = m & 31;
                    int jk = k0 + sc4 * 4;
                    const float4 ap = *(const float4*)(ws + WS_APOW + (size_t)i * P2 + jk);
                    const float4 cr = *(const float4*)(XC + g * P2 + jk);
                    f = cfma2(ap, cr, f);
                }
                ushort4 h4, l4;
                split_bf16(f.x, h4.x, l4.x);
                split_bf16(f.y, h4.y, l4.y);
                split_bf16(f.z, h4.z, l4.z);
                split_bf16(f.w, h4.w, l4.w);
                *(ushort4*)(&Ah[p][m * SAK + sc4 * 4]) = h4;
                *(ushort4*)(&Al[p][m * SAK + sc4 * 4]) = l4;
            }
        }
        // prefetch next k-slice of A (global)
        if (kt < 7) {
            f0 = *(const float4*)(A + (size_t)(l0 + sm0) * 256 + k0 + 32 + sc4 * 4);
            f1 = *(const float4*)(A + (size_t)(l0 + sm1) * 256 + k0 + 32 + sc4 * 4);
        }
        // b-frags straight from global (L1/L2-resident weights)
        short8 bh[8], blo[8];
        #pragma unroll
        for (int nf = 0; nf < 8; nf++) {
            bh[nf]  = *(const short8*)(WhB + (size_t)nf * 16 * 256 + k0);
            blo[nf] = *(const short8*)(WlB + (size_t)nf * 16 * 256 + k0);
        }
        __syncthreads();   // LDS buf p ready
        short8 ah[2], alo[2];
        #pragma unroll
        for (int mf = 0; mf < 2; mf++) {
            int m = wm * 32 + mf * 16 + lane16;
            ah[mf]  = *(const short8*)(&Ah[p][m * SAK + quad * 8]);
            alo[mf] = *(const short8*)(&Al[p][m * SAK + quad * 8]);
        }
        #pragma unroll
        for (int mf = 0; mf < 2; mf++)
            #pragma unroll
            for (int nf = 0; nf < 8; nf++) {
                acc[mf][nf] = __builtin_amdgcn_mfma_f32_16x16x32_bf16(ah[mf],  bh[nf],  acc[mf][nf], 0, 0, 0);
                acc[mf][nf] = __builtin_amdgcn_mfma_f32_16x16x32_bf16(ah[mf],  blo[nf], acc[mf][nf], 0, 0, 0);
                acc[mf][nf] = __builtin_amdgcn_mfma_f32_16x16x32_bf16(alo[mf], bh[nf],  acc[mf][nf], 0, 0, 0);
            }
        __syncthreads();   // reads of buf p done before it is overwritten
    }

    // epilogue: C/D layout col=lane&15, row=quad*4+reg
    #pragma unroll
    for (int mf = 0; mf < 2; mf++) {
        #pragma unroll
        for (int nf = 0; nf < 8; nf++) {
            int row0 = l0 + wm * 32 + mf * 16 + quad * 4;
            int col  = wn * 128 + nf * 16 + lane16;
            #pragma unroll
            for (int r = 0; r < 4; r++) {
                float v = acc[mf][nf][r];
                if (EPI) {
                    v += Dv[col] * U[(size_t)(row0 + r) * 256 + col];
                }
                Cmat[(size_t)(row0 + r) * 256 + col] = v;
            }
        }
    }

    // --- SCAN epilogue: in-place local scan of the 4 chunks + E_b ---------
    if (SCAN) {
        __syncthreads();   // full C tile visible (vmcnt drained by barrier)
        if (wave < 4) {
            const float4 Alb = *(const float4*)(ws + WS_LB + 4 * lane);
            float* base = Cmat + (size_t)(l0 + wave * 32) * 256 + 4 * lane;
            float4 x = make_float4(0.f, 0.f, 0.f, 0.f);
            #pragma unroll 8
            for (int i = 0; i < T_CHUNK; i++) {
                const float4 f = *(const float4*)(base + (size_t)i * 256);
                x = cfma2(Alb, x, f);
                *(float4*)(base + (size_t)i * 256) = x;
            }
            *(float4*)(XC + wave * P2 + 4 * lane) = x;
        }
        __syncthreads();
        if (wave == 0) {
            const float4 A32 = *(const float4*)(ws + WS_A32 + 4 * lane);
            float4 e = *(const float4*)(XC + 4 * lane);
            #pragma unroll
            for (int c = 1; c < 4; c++)
                e = cfma2(A32, e, *(const float4*)(XC + c * P2 + 4 * lane));
            *(float4*)(Eout + (size_t)blk * P2 + 4 * lane) = e;
        }
    }
}

// ---------------------------------------------------------------------------
extern "C" void kernel_launch(void* const* d_in, const int* in_sizes, int n_in,
                              void* d_out, int out_size, void* d_ws, size_t ws_size,
                              hipStream_t stream) {
    const float* lre   = (const float*)d_in[0];  // Lambda_re (P)
    const float* lim   = (const float*)d_in[1];  // Lambda_im (P)
    const float* B     = (const float*)d_in[2];  // (P,H,2)
    const float* C     = (const float*)d_in[3];  // (H,P,2)
    const float* D     = (const float*)d_in[4];  // (H)
    const float* lstep = (const float*)d_in[5];  // (P)
    const float* u     = (const float*)d_in[6];  // (L,H)
    float* out = (float*)d_out;                  // (L,H) -- also Bu/xs scratch
    float* ws  = (float*)d_ws;
    ushort* wpk = (ushort*)(ws + WS_PACKS);
    ushort* w1h = wpk;
    ushort* w1l = wpk + 65536;
    ushort* w2h = wpk + 131072;
    ushort* w2l = wpk + 196608;

    k_setup_p<<<1, 128, 0, stream>>>(lre, lim, lstep, ws);
    k_setup_mats<<<64, 256, 0, stream>>>(B, C, ws + WS_COEF, w1h, w1l, w2h, w2l);
    // GEMM1: Bu = u @ W1 -> d_out, fused local scan + segment summaries E
    k_gemm_mfma<false, false, true><<<NBLK, 512, 0, stream>>>(
        u, w1h, w1l, out, nullptr, nullptr, ws, ws + WS_E, nullptr);
    // carry across 256 segments
    k_carry<<<1, 64, 0, stream>>>(ws + WS_E, ws + WS_CB, ws + WS_A128);
    // GEMM2: out = (xs_local + Lb^{i+1} carry) @ W2 + D*u  (in place)
    k_gemm_mfma<true, true, false><<<NBLK, 512, 0, stream>>>(
        out, w2h, w2l, out, D, u, ws, nullptr, ws + WS_CB);
}